// Round 6
// baseline (906.520 us; speedup 1.0000x reference)
//
#include <hip/hip_runtime.h>
#include <hip/hip_bf16.h>

#define DIM 128
#define N_SEG 100000
#define N_TOT (N_SEG + 1)  // offsets array length
#define NB 98              // ceil(N_TOT / 1024)

typedef __attribute__((ext_vector_type(8))) __bf16 bf16x8;
typedef __attribute__((ext_vector_type(4))) float f32x4;

// ---- d_ws layout (u32 element offsets) -------------------------------------
// [0] flag (idx width probe)   [1] ucnt (number of work units)
#define WS_OFF 64                    // off[N_TOT]: counts -> exclusive offsets
#define WS_RUN (WS_OFF + N_TOT + 1)  // run[N_SEG]: rank-scatter cursors
#define WS_BSUM (WS_RUN + N_SEG)     // bsum[128]
#define WS_BPRE (WS_BSUM + 128)      // bpre[128]
#define WS_UNITS (WS_BPRE + 128)     // uint2 units[200K] (400K u32, 8B-aligned)
#define WS_ORDER (WS_UNITS + 400000) // order[1.6M]
// total ~= 2.2M u32 = 8.8 MB

// ---------------------------------------------------------------------------
// Probe: int64 index => every odd 32-bit word is 0. flag=1 => int32 layout.
// ---------------------------------------------------------------------------
__global__ void idx_probe_kernel(const unsigned* __restrict__ idx32,
                                 unsigned* __restrict__ flag, int n) {
  unsigned v = 0;
  const int stride = gridDim.x * blockDim.x;
  for (int i = blockIdx.x * blockDim.x + threadIdx.x; i < n; i += stride)
    v |= idx32[2 * i + 1];
  if (v) atomicOr(flag, 1u);
}

// vectorized histogram: uint4 = 2 int64 elems or 4 int32 elems
__global__ void hist_kernel(const uint4* __restrict__ idx4,
                            const unsigned* __restrict__ flag,
                            unsigned* __restrict__ cnt, int n) {
  const bool idx64 = (*flag == 0u);
  const int stride = gridDim.x * blockDim.x;
  const int t0 = blockIdx.x * blockDim.x + threadIdx.x;
  if (idx64) {
    const int nv = n >> 1;  // uint4 count
    for (int i = t0; i < nv; i += stride) {
      const uint4 v = idx4[i];
      atomicAdd(&cnt[v.x], 1u);
      atomicAdd(&cnt[v.z], 1u);
    }
  } else {
    const int nv = n >> 2;
    for (int i = t0; i < nv; i += stride) {
      const uint4 v = idx4[i];
      atomicAdd(&cnt[v.x], 1u);
      atomicAdd(&cnt[v.y], 1u);
      atomicAdd(&cnt[v.z], 1u);
      atomicAdd(&cnt[v.w], 1u);
    }
  }
}

// ---- coalesced 3-phase exclusive scan over off[N_TOT] -----------------------
__global__ __launch_bounds__(1024) void scan_bsum(const unsigned* __restrict__ off,
                                                  unsigned* __restrict__ bsum) {
  __shared__ unsigned ws[16];
  const int t = threadIdx.x;
  const int i = blockIdx.x * 1024 + t;
  unsigned v = (i < N_TOT) ? off[i] : 0u;
#pragma unroll
  for (int d = 1; d < 64; d <<= 1) v += __shfl_xor(v, d);
  if ((t & 63) == 0) ws[t >> 6] = v;
  __syncthreads();
  if (t == 0) {
    unsigned s = 0;
#pragma unroll
    for (int w = 0; w < 16; ++w) s += ws[w];
    bsum[blockIdx.x] = s;
  }
}

__global__ __launch_bounds__(128) void scan_btop(unsigned* __restrict__ bsum,
                                                 unsigned* __restrict__ bpre) {
  __shared__ unsigned part[128];
  const int t = threadIdx.x;
  unsigned v = (t < NB) ? bsum[t] : 0u;
  part[t] = v;
  __syncthreads();
  for (int d = 1; d < 128; d <<= 1) {
    const unsigned u = (t >= d) ? part[t - d] : 0u;
    __syncthreads();
    part[t] += u;
    __syncthreads();
  }
  bpre[t] = part[t] - v;  // exclusive
}

__global__ __launch_bounds__(1024) void scan_fixup(unsigned* __restrict__ off,
                                                   unsigned* __restrict__ run,
                                                   const unsigned* __restrict__ bpre) {
  __shared__ unsigned wsum[16], wpre[16];
  const int t = threadIdx.x;
  const int lane = t & 63;
  const int wv = t >> 6;
  const int i = blockIdx.x * 1024 + t;
  const unsigned v = (i < N_TOT) ? off[i] : 0u;
  unsigned s = v;
#pragma unroll
  for (int d = 1; d < 64; d <<= 1) {
    const unsigned u = __shfl_up(s, d);
    if (lane >= d) s += u;
  }
  if (lane == 63) wsum[wv] = s;
  __syncthreads();
  if (t < 16) {
    unsigned w = wsum[t];
    unsigned ps = w;
#pragma unroll
    for (int d = 1; d < 16; d <<= 1) {
      const unsigned u = __shfl_up(ps, d, 16);
      if (t >= d) ps += u;
    }
    wpre[t] = ps - w;  // exclusive across waves
  }
  __syncthreads();
  const unsigned excl = (s - v) + wpre[wv] + bpre[blockIdx.x];
  if (i < N_TOT) off[i] = excl;
  if (i < N_SEG) run[i] = excl;
}

// vectorized rank-scatter: uint4 = 2 int64 elems or 4 int32 elems
__global__ void rank_kernel(const uint4* __restrict__ idx4,
                            const unsigned* __restrict__ flag,
                            unsigned* __restrict__ run,
                            unsigned* __restrict__ order, int n) {
  const bool idx64 = (*flag == 0u);
  const int stride = gridDim.x * blockDim.x;
  const int t0 = blockIdx.x * blockDim.x + threadIdx.x;
  if (idx64) {
    const int nv = n >> 1;
    for (int i = t0; i < nv; i += stride) {
      const uint4 v = idx4[i];
      unsigned p0 = atomicAdd(&run[v.x], 1u);
      order[p0] = 2u * i;
      unsigned p1 = atomicAdd(&run[v.z], 1u);
      order[p1] = 2u * i + 1u;
    }
  } else {
    const int nv = n >> 2;
    for (int i = t0; i < nv; i += stride) {
      const uint4 v = idx4[i];
      unsigned p0 = atomicAdd(&run[v.x], 1u);
      order[p0] = 4u * i;
      unsigned p1 = atomicAdd(&run[v.y], 1u);
      order[p1] = 4u * i + 1u;
      unsigned p2 = atomicAdd(&run[v.z], 1u);
      order[p2] = 4u * i + 2u;
      unsigned p3 = atomicAdd(&run[v.w], 1u);
      order[p3] = 4u * i + 3u;
    }
  }
}

// ---------------------------------------------------------------------------
// Build flattened work units (<=32 rows of one segment) AND zero the few out
// rows not covered by solo stores: empty segments and multi-unit segments.
// entry.x = start offset into order[]; entry.y = seg(17b)|(cnt-1)<<17|solo<<23
// ---------------------------------------------------------------------------
__global__ void unit_build(const unsigned* __restrict__ off,
                           uint2* __restrict__ units,
                           unsigned* __restrict__ ucnt,
                           float* __restrict__ out) {
  const int s = blockIdx.x * blockDim.x + threadIdx.x;
  if (s >= N_SEG) return;
  const unsigned b = off[s];
  const unsigned c = off[s + 1] - b;
  const unsigned nu = (c + 31) >> 5;
  if (c == 0 || nu > 1) {  // rare: ~11 empty + ~20 multi-unit rows
    f32x4* orow = (f32x4*)(out + (size_t)s * DIM);
    for (int k = 0; k < DIM / 4; ++k) orow[k] = (f32x4){0.f, 0.f, 0.f, 0.f};
    if (c == 0) return;
  }
  const unsigned pos = atomicAdd(ucnt, nu);
  const unsigned solo = (nu == 1) ? (1u << 23) : 0u;
  for (unsigned t = 0; t < nu; ++t) {
    const unsigned cnt = min(32u, c - 32u * t);
    uint2 ent;
    ent.x = b + 32u * t;
    ent.y = (unsigned)s | ((cnt - 1u) << 17) | solo;
    units[pos + t] = ent;
  }
}

// ---------------------------------------------------------------------------
// Main: one wave per unit (<=32 rows of one segment). Gather rows via
// order[], h = relu(e@W^T + b) via MFMA against LDS-resident W fragments,
// masked fold into register column sums, cross-lane reduce, then ONE
// store (solo) or atomic-add (rare multi-unit segment) per out row.
// Pipeline: prefetch next unit's descriptor; issue both tiles' row ids
// up front; tile-1 path is wave-uniform-skipped when cnt<=16.
//
// Fragment layouts (mfma_f32_16x16x32_bf16, m89-verified):
//   A (lane l, elem j): e[row_{l&15}][32t + (l>>4)*8 + j]
//   B (lane l, elem j): W[k0*16 + (l&15)][32t + (l>>4)*8 + j]   (LDS frags)
//   C/D (lane l, reg r): h[tile row (l>>4)*4 + r][k0*16 + (l&15)]
// ---------------------------------------------------------------------------
__device__ __forceinline__ void process_tile(
    const float* __restrict__ e, const bf16x8* __restrict__ wlds,
    const float* bias, unsigned row, int tbase, int cnt, int lg, int lane,
    float* colsum) {
  const float* erow = e + (size_t)row * DIM + lg * 8;
  bf16x8 afrag[4];
#pragma unroll
  for (int t = 0; t < 4; ++t) {
    f32x4 a0 = *(const f32x4*)(erow + t * 32);
    f32x4 a1 = *(const f32x4*)(erow + t * 32 + 4);
    bf16x8 f;
    f[0] = (__bf16)a0[0]; f[1] = (__bf16)a0[1];
    f[2] = (__bf16)a0[2]; f[3] = (__bf16)a0[3];
    f[4] = (__bf16)a1[0]; f[5] = (__bf16)a1[1];
    f[6] = (__bf16)a1[2]; f[7] = (__bf16)a1[3];
    afrag[t] = f;
  }
#pragma unroll
  for (int half = 0; half < 2; ++half) {
    f32x4 acc[4];
#pragma unroll
    for (int k = 0; k < 4; ++k) acc[k] = (f32x4){0.f, 0.f, 0.f, 0.f};
#pragma unroll
    for (int t = 0; t < 4; ++t) {
#pragma unroll
      for (int k = 0; k < 4; ++k) {
        bf16x8 bf = wlds[((half * 4 + k) * 4 + t) * 64 + lane];
        acc[k] = __builtin_amdgcn_mfma_f32_16x16x32_bf16(afrag[t], bf,
                                                         acc[k], 0, 0, 0);
      }
    }
#pragma unroll
    for (int r = 0; r < 4; ++r) {
      const bool valid = (tbase + lg * 4 + r) < cnt;
#pragma unroll
      for (int k = 0; k < 4; ++k) {
        const float v = fmaxf(acc[k][r] + bias[half * 4 + k], 0.f);
        colsum[half * 4 + k] += valid ? v : 0.f;
      }
    }
  }
}

__global__ __launch_bounds__(256, 4) void fused_main(
    const float* __restrict__ e, const float* __restrict__ W,
    const float* __restrict__ bias_p, const unsigned* __restrict__ order,
    const uint2* __restrict__ units, const unsigned* __restrict__ ucnt,
    float* __restrict__ out) {
  __shared__ bf16x8 wlds[2048];  // 32 KiB: [k0][t][lane] fragment-major

  const int tid = threadIdx.x;
  const int wave = tid >> 6;
  const int lane = tid & 63;
  const int lr = lane & 15;
  const int lg = lane >> 4;

  // one-time: stage W as bf16 fragments into LDS
#pragma unroll
  for (int j = 0; j < 8; ++j) {
    const int g = (tid << 3) | j;
    const int gl = g & 63;
    const int tt = (g >> 6) & 3;
    const int k0 = g >> 8;
    const int row = k0 * 16 + (gl & 15);
    const int col = tt * 32 + (gl >> 4) * 8;
    const float* src = W + (size_t)row * DIM + col;
    f32x4 w0 = *(const f32x4*)src;
    f32x4 w1 = *(const f32x4*)(src + 4);
    bf16x8 f;
    f[0] = (__bf16)w0[0]; f[1] = (__bf16)w0[1];
    f[2] = (__bf16)w0[2]; f[3] = (__bf16)w0[3];
    f[4] = (__bf16)w1[0]; f[5] = (__bf16)w1[1];
    f[6] = (__bf16)w1[2]; f[7] = (__bf16)w1[3];
    wlds[g] = f;
  }
  __syncthreads();

  float bias[8];
#pragma unroll
  for (int k0 = 0; k0 < 8; ++k0) bias[k0] = bias_p[k0 * 16 + lr];

  const int n_units = (int)*ucnt;
  const int wid = blockIdx.x * 4 + wave;
  const int nw = gridDim.x * 4;
  if (wid >= n_units) return;

  uint2 ent = units[wid];
  for (int u = wid; u < n_units; u += nw) {
    // prefetch next unit's descriptor (hides under this unit's work)
    uint2 ent_next = ent;
    if (u + nw < n_units) ent_next = units[u + nw];

    const int base = (int)ent.x;
    const int seg = (int)(ent.y & 0x1FFFFu);
    const int cnt = (int)((ent.y >> 17) & 31u) + 1;
    const bool solo = (ent.y >> 23) & 1u;
    const bool two = cnt > 16;  // wave-uniform

    // issue both tiles' row ids up front
    const unsigned row0 = order[base + (lr < cnt ? lr : cnt - 1)];
    unsigned row1 = 0;
    if (two) row1 = order[base + (16 + lr < cnt ? 16 + lr : cnt - 1)];

    float colsum[8] = {0.f, 0.f, 0.f, 0.f, 0.f, 0.f, 0.f, 0.f};
    process_tile(e, wlds, bias, row0, 0, cnt, lg, lane, colsum);
    if (two) process_tile(e, wlds, bias, row1, 16, cnt, lg, lane, colsum);

    // reduce over the 4 lg groups; lanes 0..15 hold the 128 column sums
#pragma unroll
    for (int k0 = 0; k0 < 8; ++k0) {
      float s = colsum[k0];
      s += __shfl_xor(s, 16);
      s += __shfl_xor(s, 32);
      colsum[k0] = s;
    }
    if (lg == 0) {
      float* orow = out + (size_t)seg * DIM + lr;
      if (solo) {
#pragma unroll
        for (int k0 = 0; k0 < 8; ++k0) orow[k0 * 16] = colsum[k0];
      } else {
#pragma unroll
        for (int k0 = 0; k0 < 8; ++k0)
          unsafeAtomicAdd(orow + k0 * 16, colsum[k0]);
      }
    }
    ent = ent_next;
  }
}

extern "C" void kernel_launch(void* const* d_in, const int* in_sizes, int n_in,
                              void* d_out, int out_size, void* d_ws, size_t ws_size,
                              hipStream_t stream) {
  const float* e = (const float*)d_in[0];
  const int* idx = (const int*)d_in[1];
  const float* W = (const float*)d_in[2];
  const float* b = (const float*)d_in[3];
  float* out = (float*)d_out;
  unsigned* ws32 = (unsigned*)d_ws;

  const int n_e = in_sizes[0] / DIM;  // 1,600,000 rows

  // zero flag + ucnt + histogram region (out rows handled by unit_build)
  hipMemsetAsync(d_ws, 0, (size_t)WS_RUN * sizeof(unsigned), stream);

  idx_probe_kernel<<<256, 256, 0, stream>>>((const unsigned*)idx, ws32,
                                            n_e / 2);
  hist_kernel<<<1024, 256, 0, stream>>>((const uint4*)idx, ws32, ws32 + WS_OFF,
                                        n_e);
  scan_bsum<<<NB, 1024, 0, stream>>>(ws32 + WS_OFF, ws32 + WS_BSUM);
  scan_btop<<<1, 128, 0, stream>>>(ws32 + WS_BSUM, ws32 + WS_BPRE);
  scan_fixup<<<NB, 1024, 0, stream>>>(ws32 + WS_OFF, ws32 + WS_RUN,
                                      ws32 + WS_BPRE);
  rank_kernel<<<1024, 256, 0, stream>>>((const uint4*)idx, ws32, ws32 + WS_RUN,
                                        ws32 + WS_ORDER, n_e);
  unit_build<<<(N_SEG + 255) / 256, 256, 0, stream>>>(
      ws32 + WS_OFF, (uint2*)(ws32 + WS_UNITS), ws32 + 1, out);
  fused_main<<<2048, 256, 0, stream>>>(e, W, b, ws32 + WS_ORDER,
                                       (const uint2*)(ws32 + WS_UNITS),
                                       ws32 + 1, out);
}

// Round 7
// 459.094 us; speedup vs baseline: 1.9746x; 1.9746x over previous
//
#include <hip/hip_runtime.h>
#include <hip/hip_bf16.h>

#define DIM 128
#define N_SEG 100000
#define N_TOT (N_SEG + 1)  // offsets array length
#define NB 98              // ceil(N_TOT / 1024)

typedef __attribute__((ext_vector_type(8))) __bf16 bf16x8;
typedef __attribute__((ext_vector_type(4))) float f32x4;

// ---- d_ws layout (u32 element offsets) -------------------------------------
// [0] flag (idx width probe)   [1] ucnt (number of work units)
#define WS_OFF 64                    // off[N_TOT]: counts -> exclusive offsets
#define WS_RUN (WS_OFF + N_TOT + 1)  // run[N_SEG]: rank-scatter cursors
#define WS_BSUM (WS_RUN + N_SEG)     // bsum[128]
#define WS_BPRE (WS_BSUM + 128)      // bpre[128]
#define WS_UNITS (WS_BPRE + 128)     // uint2 units[300K] (600K u32, 8B-aligned)
#define WS_ORDER (WS_UNITS + 600000) // order[1.6M]
// total ~= 2.4M u32 = 9.6 MB

// ---------------------------------------------------------------------------
// Probe: int64 index => every odd 32-bit word is 0. flag=1 => int32 layout.
// ---------------------------------------------------------------------------
__global__ void idx_probe_kernel(const unsigned* __restrict__ idx32,
                                 unsigned* __restrict__ flag, int n) {
  unsigned v = 0;
  const int stride = gridDim.x * blockDim.x;
  for (int i = blockIdx.x * blockDim.x + threadIdx.x; i < n; i += stride)
    v |= idx32[2 * i + 1];
  if (v) atomicOr(flag, 1u);
}

// vectorized histogram: uint4 = 2 int64 elems or 4 int32 elems
__global__ void hist_kernel(const uint4* __restrict__ idx4,
                            const unsigned* __restrict__ flag,
                            unsigned* __restrict__ cnt, int n) {
  const bool idx64 = (*flag == 0u);
  const int stride = gridDim.x * blockDim.x;
  const int t0 = blockIdx.x * blockDim.x + threadIdx.x;
  if (idx64) {
    const int nv = n >> 1;  // uint4 count
    for (int i = t0; i < nv; i += stride) {
      const uint4 v = idx4[i];
      atomicAdd(&cnt[v.x], 1u);
      atomicAdd(&cnt[v.z], 1u);
    }
  } else {
    const int nv = n >> 2;
    for (int i = t0; i < nv; i += stride) {
      const uint4 v = idx4[i];
      atomicAdd(&cnt[v.x], 1u);
      atomicAdd(&cnt[v.y], 1u);
      atomicAdd(&cnt[v.z], 1u);
      atomicAdd(&cnt[v.w], 1u);
    }
  }
}

// ---- coalesced 3-phase exclusive scan over off[N_TOT] -----------------------
__global__ __launch_bounds__(1024) void scan_bsum(const unsigned* __restrict__ off,
                                                  unsigned* __restrict__ bsum) {
  __shared__ unsigned ws[16];
  const int t = threadIdx.x;
  const int i = blockIdx.x * 1024 + t;
  unsigned v = (i < N_TOT) ? off[i] : 0u;
#pragma unroll
  for (int d = 1; d < 64; d <<= 1) v += __shfl_xor(v, d);
  if ((t & 63) == 0) ws[t >> 6] = v;
  __syncthreads();
  if (t == 0) {
    unsigned s = 0;
#pragma unroll
    for (int w = 0; w < 16; ++w) s += ws[w];
    bsum[blockIdx.x] = s;
  }
}

__global__ __launch_bounds__(128) void scan_btop(unsigned* __restrict__ bsum,
                                                 unsigned* __restrict__ bpre) {
  __shared__ unsigned part[128];
  const int t = threadIdx.x;
  unsigned v = (t < NB) ? bsum[t] : 0u;
  part[t] = v;
  __syncthreads();
  for (int d = 1; d < 128; d <<= 1) {
    const unsigned u = (t >= d) ? part[t - d] : 0u;
    __syncthreads();
    part[t] += u;
    __syncthreads();
  }
  bpre[t] = part[t] - v;  // exclusive
}

__global__ __launch_bounds__(1024) void scan_fixup(unsigned* __restrict__ off,
                                                   unsigned* __restrict__ run,
                                                   const unsigned* __restrict__ bpre) {
  __shared__ unsigned wsum[16], wpre[16];
  const int t = threadIdx.x;
  const int lane = t & 63;
  const int wv = t >> 6;
  const int i = blockIdx.x * 1024 + t;
  const unsigned v = (i < N_TOT) ? off[i] : 0u;
  unsigned s = v;
#pragma unroll
  for (int d = 1; d < 64; d <<= 1) {
    const unsigned u = __shfl_up(s, d);
    if (lane >= d) s += u;
  }
  if (lane == 63) wsum[wv] = s;
  __syncthreads();
  if (t < 16) {
    unsigned w = wsum[t];
    unsigned ps = w;
#pragma unroll
    for (int d = 1; d < 16; d <<= 1) {
      const unsigned u = __shfl_up(ps, d, 16);
      if (t >= d) ps += u;
    }
    wpre[t] = ps - w;  // exclusive across waves
  }
  __syncthreads();
  const unsigned excl = (s - v) + wpre[wv] + bpre[blockIdx.x];
  if (i < N_TOT) off[i] = excl;
  if (i < N_SEG) run[i] = excl;
}

// vectorized rank-scatter: uint4 = 2 int64 elems or 4 int32 elems
__global__ void rank_kernel(const uint4* __restrict__ idx4,
                            const unsigned* __restrict__ flag,
                            unsigned* __restrict__ run,
                            unsigned* __restrict__ order, int n) {
  const bool idx64 = (*flag == 0u);
  const int stride = gridDim.x * blockDim.x;
  const int t0 = blockIdx.x * blockDim.x + threadIdx.x;
  if (idx64) {
    const int nv = n >> 1;
    for (int i = t0; i < nv; i += stride) {
      const uint4 v = idx4[i];
      unsigned p0 = atomicAdd(&run[v.x], 1u);
      order[p0] = 2u * i;
      unsigned p1 = atomicAdd(&run[v.z], 1u);
      order[p1] = 2u * i + 1u;
    }
  } else {
    const int nv = n >> 2;
    for (int i = t0; i < nv; i += stride) {
      const uint4 v = idx4[i];
      unsigned p0 = atomicAdd(&run[v.x], 1u);
      order[p0] = 4u * i;
      unsigned p1 = atomicAdd(&run[v.y], 1u);
      order[p1] = 4u * i + 1u;
      unsigned p2 = atomicAdd(&run[v.z], 1u);
      order[p2] = 4u * i + 2u;
      unsigned p3 = atomicAdd(&run[v.w], 1u);
      order[p3] = 4u * i + 3u;
    }
  }
}

// ---------------------------------------------------------------------------
// Build flattened work units: each covers <=16 rows of one segment (uniform,
// single-tile). entry.x = start into order[];
// entry.y = seg(17b) | (cnt-1)<<17 (4b) | solo<<23
// ---------------------------------------------------------------------------
__global__ void unit_build(const unsigned* __restrict__ off,
                           uint2* __restrict__ units,
                           unsigned* __restrict__ ucnt) {
  const int s = blockIdx.x * blockDim.x + threadIdx.x;
  if (s >= N_SEG) return;
  const unsigned b = off[s];
  const unsigned c = off[s + 1] - b;
  if (c == 0) return;  // out row pre-zeroed by memset
  const unsigned nu = (c + 15) >> 4;
  const unsigned pos = atomicAdd(ucnt, nu);
  const unsigned solo = (nu == 1) ? (1u << 23) : 0u;
  for (unsigned t = 0; t < nu; ++t) {
    const unsigned cnt = min(16u, c - 16u * t);
    uint2 ent;
    ent.x = b + 16u * t;
    ent.y = (unsigned)s | ((cnt - 1u) << 17) | solo;
    units[pos + t] = ent;
  }
}

// ---------------------------------------------------------------------------
// Main: one wave per 16-row unit, 3-deep rotating prefetch pipeline:
//   descriptors 3 ahead, order-ids 2 ahead, e-row data 1 ahead.
// Every vmem wait is >= 1 iteration old -> dependent-chain latency hidden by
// ILP (runs fat at (256,2): (256,4)'s 128-reg cap spilled => GBs of scratch
// HBM traffic, R3/R6 evidence).
//
// Fragment layouts (mfma_f32_16x16x32_bf16, m89-verified):
//   A (lane l, elem j): e[row_{l&15}][32t + (l>>4)*8 + j]
//   B (lane l, elem j): W[k0*16 + (l&15)][32t + (l>>4)*8 + j]   (LDS frags)
//   C/D (lane l, reg r): h[tile row (l>>4)*4 + r][k0*16 + (l&15)]
// ---------------------------------------------------------------------------
__global__ __launch_bounds__(256, 2) void fused_main(
    const float* __restrict__ e, const float* __restrict__ W,
    const float* __restrict__ bias_p, const unsigned* __restrict__ order,
    const uint2* __restrict__ units, const unsigned* __restrict__ ucnt,
    float* __restrict__ out) {
  __shared__ bf16x8 wlds[2048];  // 32 KiB: [k0][t][lane] fragment-major

  const int tid = threadIdx.x;
  const int wave = tid >> 6;
  const int lane = tid & 63;
  const int lr = lane & 15;
  const int lg = lane >> 4;

  // one-time: stage W as bf16 fragments into LDS
#pragma unroll
  for (int j = 0; j < 8; ++j) {
    const int g = (tid << 3) | j;
    const int gl = g & 63;
    const int tt = (g >> 6) & 3;
    const int k0 = g >> 8;
    const int row = k0 * 16 + (gl & 15);
    const int col = tt * 32 + (gl >> 4) * 8;
    const float* src = W + (size_t)row * DIM + col;
    f32x4 w0 = *(const f32x4*)src;
    f32x4 w1 = *(const f32x4*)(src + 4);
    bf16x8 f;
    f[0] = (__bf16)w0[0]; f[1] = (__bf16)w0[1];
    f[2] = (__bf16)w0[2]; f[3] = (__bf16)w0[3];
    f[4] = (__bf16)w1[0]; f[5] = (__bf16)w1[1];
    f[6] = (__bf16)w1[2]; f[7] = (__bf16)w1[3];
    wlds[g] = f;
  }
  __syncthreads();

  float bias[8];
#pragma unroll
  for (int k0 = 0; k0 < 8; ++k0) bias[k0] = bias_p[k0 * 16 + lr];

  const int n_units = (int)*ucnt;
  const int wid = blockIdx.x * 4 + wave;
  const int nw = gridDim.x * 4;
  if (wid >= n_units) return;

  // ---- prologue: fill the 3-deep pipeline ---------------------------------
  // eA = unit u, eB = u+nw, eC = u+2nw (clamped to last valid for loads)
  uint2 eA = units[wid];
  uint2 eB = units[(wid + nw < n_units) ? wid + nw : n_units - 1];
  uint2 eC = units[(wid + 2 * nw < n_units) ? wid + 2 * nw : n_units - 1];

  // ids + data for current unit (serial, once)
  {
    const int cA = (int)((eA.y >> 17) & 15u) + 1;
    const unsigned idA = order[eA.x + (lr < cA ? lr : cA - 1)];
    (void)idA;
  }
  const int cA0 = (int)((eA.y >> 17) & 15u) + 1;
  unsigned idCur = order[eA.x + (lr < cA0 ? lr : cA0 - 1)];
  f32x4 eload[8];
  {
    const float* erow = e + (size_t)idCur * DIM + lg * 8;
#pragma unroll
    for (int t = 0; t < 4; ++t) {
      eload[2 * t]     = *(const f32x4*)(erow + t * 32);
      eload[2 * t + 1] = *(const f32x4*)(erow + t * 32 + 4);
    }
  }
  // ids for u+nw (from eB)
  const int cB0 = (int)((eB.y >> 17) & 15u) + 1;
  unsigned idNext = order[eB.x + (lr < cB0 ? lr : cB0 - 1)];

  for (int u = wid; u < n_units; u += nw) {
    // decode CURRENT before rotation
    const int seg = (int)(eA.y & 0x1FFFFu);
    const int cnt = (int)((eA.y >> 17) & 15u) + 1;
    const bool solo = (eA.y >> 23) & 1u;

    // 1. convert current e-tile (vmcnt wait: eload issued >=1 iter ago)
    bf16x8 afrag[4];
#pragma unroll
    for (int t = 0; t < 4; ++t) {
      f32x4 a0 = eload[2 * t], a1 = eload[2 * t + 1];
      bf16x8 f;
      f[0] = (__bf16)a0[0]; f[1] = (__bf16)a0[1];
      f[2] = (__bf16)a0[2]; f[3] = (__bf16)a0[3];
      f[4] = (__bf16)a1[0]; f[5] = (__bf16)a1[1];
      f[6] = (__bf16)a1[2]; f[7] = (__bf16)a1[3];
      afrag[t] = f;
    }

    // 2. issue data loads for u+nw (ids loaded last iteration -> no stall)
    {
      const float* erow = e + (size_t)idNext * DIM + lg * 8;
#pragma unroll
      for (int t = 0; t < 4; ++t) {
        eload[2 * t]     = *(const f32x4*)(erow + t * 32);
        eload[2 * t + 1] = *(const f32x4*)(erow + t * 32 + 4);
      }
    }
    // 3. issue ids for u+2nw (descriptor eC loaded last iteration)
    {
      const int cC = (int)((eC.y >> 17) & 15u) + 1;
      idNext = order[eC.x + (lr < cC ? lr : cC - 1)];
    }
    // 4. issue descriptor for u+3nw
    uint2 eC_next =
        units[(u + 3 * nw < n_units) ? u + 3 * nw : n_units - 1];

    // 5. MFMA (LDS operands, lgkmcnt only) — half-split keeps acc at 16 regs
    float colsum[8] = {0.f, 0.f, 0.f, 0.f, 0.f, 0.f, 0.f, 0.f};
#pragma unroll
    for (int half = 0; half < 2; ++half) {
      f32x4 acc[4];
#pragma unroll
      for (int k = 0; k < 4; ++k) acc[k] = (f32x4){0.f, 0.f, 0.f, 0.f};
#pragma unroll
      for (int t = 0; t < 4; ++t) {
#pragma unroll
        for (int k = 0; k < 4; ++k) {
          bf16x8 bf = wlds[((half * 4 + k) * 4 + t) * 64 + lane];
          acc[k] = __builtin_amdgcn_mfma_f32_16x16x32_bf16(afrag[t], bf,
                                                           acc[k], 0, 0, 0);
        }
      }
#pragma unroll
      for (int r = 0; r < 4; ++r) {
        const bool valid = (lg * 4 + r) < cnt;
#pragma unroll
        for (int k = 0; k < 4; ++k) {
          const float v = fmaxf(acc[k][r] + bias[half * 4 + k], 0.f);
          colsum[half * 4 + k] += valid ? v : 0.f;
        }
      }
    }

    // 6. cross-lane reduce; lanes 0..15 hold the 128 column sums
#pragma unroll
    for (int k0 = 0; k0 < 8; ++k0) {
      float s = colsum[k0];
      s += __shfl_xor(s, 16);
      s += __shfl_xor(s, 32);
      colsum[k0] = s;
    }
    if (lg == 0) {
      float* orow = out + (size_t)seg * DIM + lr;
      if (solo) {
#pragma unroll
        for (int k0 = 0; k0 < 8; ++k0) orow[k0 * 16] = colsum[k0];
      } else {
#pragma unroll
        for (int k0 = 0; k0 < 8; ++k0)
          unsafeAtomicAdd(orow + k0 * 16, colsum[k0]);
      }
    }

    // 7. rotate pipeline
    eA = eB;
    eB = eC;
    eC = eC_next;
  }
}

extern "C" void kernel_launch(void* const* d_in, const int* in_sizes, int n_in,
                              void* d_out, int out_size, void* d_ws, size_t ws_size,
                              hipStream_t stream) {
  const float* e = (const float*)d_in[0];
  const int* idx = (const int*)d_in[1];
  const float* W = (const float*)d_in[2];
  const float* b = (const float*)d_in[3];
  float* out = (float*)d_out;
  unsigned* ws32 = (unsigned*)d_ws;

  const int n_e = in_sizes[0] / DIM;  // 1,600,000 rows

  // zero flag + ucnt + histogram region; out (atomic base + empty segments)
  hipMemsetAsync(d_ws, 0, (size_t)WS_RUN * sizeof(unsigned), stream);
  hipMemsetAsync(d_out, 0, (size_t)out_size * sizeof(float), stream);

  idx_probe_kernel<<<64, 256, 0, stream>>>((const unsigned*)idx, ws32,
                                           n_e / 2);
  hist_kernel<<<1024, 256, 0, stream>>>((const uint4*)idx, ws32, ws32 + WS_OFF,
                                        n_e);
  scan_bsum<<<NB, 1024, 0, stream>>>(ws32 + WS_OFF, ws32 + WS_BSUM);
  scan_btop<<<1, 128, 0, stream>>>(ws32 + WS_BSUM, ws32 + WS_BPRE);
  scan_fixup<<<NB, 1024, 0, stream>>>(ws32 + WS_OFF, ws32 + WS_RUN,
                                      ws32 + WS_BPRE);
  rank_kernel<<<1024, 256, 0, stream>>>((const uint4*)idx, ws32, ws32 + WS_RUN,
                                        ws32 + WS_ORDER, n_e);
  unit_build<<<(N_SEG + 255) / 256, 256, 0, stream>>>(
      ws32 + WS_OFF, (uint2*)(ws32 + WS_UNITS), ws32 + 1);
  fused_main<<<2048, 256, 0, stream>>>(e, W, b, ws32 + WS_ORDER,
                                       (const uint2*)(ws32 + WS_UNITS),
                                       ws32 + 1, out);
}